// Round 4
// baseline (373.535 us; speedup 1.0000x reference)
//
#include <hip/hip_runtime.h>
#include <math.h>

#define MAXDEG 20
#define NM 21               // m = 0..20
#define RANK 256
#define WPTS 2              // points per wave
#define WSLOT 4             // (point,side) slots per wave
#define PPB 8               // 4 waves * 2 points per block
#define TS 233              // Legendre slot stride in words (231 used)
#define GS 43               // trig slot stride in words (42 used)

// ---- compile-time sqrt (Newton, double) for __constant__ tables ----
constexpr double csqrt(double x) {
  double g = x < 1.0 ? 1.0 : x;
  for (int i = 0; i < 80; ++i) g = 0.5 * (g + x / g);
  return g;
}

struct Tabs {
  float ab[231][2];   // normalized recurrence coeffs, index tri(l)+m = l(l+1)/2+m
  float c1[NM];       // sqrt(2m+3)
  float pc[NM];       // folded Pbar_mm prefactor: sqrt(1/4pi)*prod(-sqrt((2k+1)/2k))*(sqrt2 if m>=1)
  constexpr Tabs() : ab{}, c1{}, pc{} {
    for (int l = 0; l <= MAXDEG; ++l)
      for (int m = 0; m <= l; ++m) {
        int i = l * (l + 1) / 2 + m;
        double a = 0.0, b = 0.0;
        if (l >= m + 2) {
          double l2 = (double)l * l, m2 = (double)m * m;
          double inv = 1.0 / (l2 - m2);
          a = csqrt((4.0 * l2 - 1.0) * inv);
          b = csqrt((2.0 * l + 1.0) * ((double)(l - 1) * (l - 1) - m2)
                    / (2.0 * l - 3.0) * inv);
        }
        ab[i][0] = (float)a; ab[i][1] = (float)b;
      }
    for (int m = 0; m <= MAXDEG; ++m) c1[m] = (float)csqrt(2.0 * m + 3.0);
    double pr = csqrt(1.0 / (4.0 * 3.14159265358979323846));
    double s2 = csqrt(2.0);
    pc[0] = (float)pr;
    for (int m = 1; m <= MAXDEG; ++m) {
      pr = -pr * csqrt((2.0 * m + 1.0) / (2.0 * m));   // Condon-Shortley folded
      pc[m] = (float)(pr * s2);                        // sqrt(2) folded for m>=1
    }
  }
};
__constant__ Tabs TB{};

// flax index k = l*(l+1)+m -> (Legendre row pi, trig row ti)
__device__ __forceinline__ void remap2(int k, int& pi, int& ti) {
  int l = (int)sqrtf((float)k);
  if (l * l > k) --l;
  if ((l + 1) * (l + 1) <= k) ++l;
  int m = k - l * (l + 1);
  int am = m < 0 ? -m : m;
  pi = 21 * am - (am * (am - 1)) / 2 + (l - am);
  ti = (m == 0) ? 0 : (m > 0 ? am : 21 + am);
}

// prep: remap the 256 (i,j) rank pairs once, packed pi|(ti<<16)
__global__ void sh_prep(const int* __restrict__ ri, const int* __restrict__ rj,
                        int2* __restrict__ w) {
  int t = threadIdx.x;
  int pi, ti, pj, tj;
  remap2(ri[t], pi, ti);
  remap2(rj[t], pj, tj);
  w[t] = make_int2(pi | (ti << 16), pj | (tj << 16));
}

// Each WAVE independently owns 2 points (4 slots): builds its private LDS
// tables (fused trig-powering + Legendre recurrence tasks), then gathers.
// No __syncthreads: cross-lane LDS visibility within a wave needs only
// s_waitcnt lgkmcnt(0) (+ sched_barrier to pin ordering).
__global__ __launch_bounds__(256, 8)
void sh_fused(const float* __restrict__ coords,
              const int* __restrict__ rand_i,
              const int* __restrict__ rand_j,
              const int2* __restrict__ w,
              float* __restrict__ out, int N) {
  __shared__ float s_tab[4][WSLOT * TS];
  __shared__ float s_tg [4][WSLOT * GS];

  const int t  = threadIdx.x;
  const int wv = t >> 6, ln = t & 63;
  const int n0 = blockIdx.x * PPB + wv * WPTS;

  // gather indices for my 4 consecutive ranks r = 4*ln + c
  int wi[4], wj[4];
  if (w) {
    int4 a = *reinterpret_cast<const int4*>(w + 4 * ln);       // (i0,j0,i1,j1)
    int4 b = *reinterpret_cast<const int4*>(w + 4 * ln + 2);   // (i2,j2,i3,j3)
    wi[0] = a.x; wj[0] = a.y; wi[1] = a.z; wj[1] = a.w;
    wi[2] = b.x; wj[2] = b.y; wi[3] = b.z; wj[3] = b.w;
  } else {
    #pragma unroll
    for (int c2 = 0; c2 < 4; ++c2) {
      int r = 4 * ln + c2;
      int pi, ti, pj, tj;
      remap2(rand_i[r], pi, ti);
      remap2(rand_j[r], pj, tj);
      wi[c2] = pi | (ti << 16);
      wj[c2] = pj | (tj << 16);
    }
  }

  float* tab = s_tab[wv];
  float* tg  = s_tg[wv];

  // ---- fused fill: 84 tasks = (m, slot), m-major for low divergence ----
  for (int task = ln; task < NM * WSLOT; task += 64) {
    const int m  = task >> 2;
    const int sl = task & 3;
    const int p  = sl >> 1, d = sl & 1;
    int n = n0 + p; if (n >= N) n = N - 1;
    const float* c = coords + (size_t)n * 6 + d * 3;
    float cx = c[0], cy = c[1], cz = c[2];
    float x = cz * rsqrtf(cx * cx + cy * cy + cz * cz);   // cos(inclination)
    x = fminf(1.f, fmaxf(-1.f, x));
    float st = sqrtf(fmaxf(0.f, 1.f - x * x));            // sin(inclination)
    float rho2 = cx * cx + cy * cy;
    float cphi = 1.f, sphi = 0.f;
    if (rho2 > 0.f) { float ir = rsqrtf(rho2); cphi = cx * ir; sphi = cy * ir; }

    // (cphi + i*sphi)^m and st^m by binary powering (<=5 squarings)
    float cm = 1.f, sm = 0.f, sp = 1.f;
    float bc = cphi, bs = sphi, bp = st;
    int mm = m;
    while (mm) {
      if (mm & 1) {
        float tc = cm * bc - sm * bs;
        sm = sm * bc + cm * bs;
        cm = tc;
        sp *= bp;
      }
      mm >>= 1;
      if (mm) {
        float t2 = bc * bc - bs * bs;
        bs = 2.f * bc * bs;
        bc = t2;
        bp *= bp;
      }
    }
    tg[sl * GS + m]      = cm;   // cos(m phi)  (m=0 -> 1)
    tg[sl * GS + 21 + m] = sm;   // sin(m phi)  (index 21 never gathered)

    float p1 = TB.pc[m] * sp;    // Pbar_mm, norm+CS+sqrt2 folded
    float* col = tab + sl * TS + (21 * m - (m * (m - 1)) / 2);
    col[0] = p1;                 // l = m
    if (m < MAXDEG) {
      float p2 = p1;
      float pcv = TB.c1[m] * x * p1;            // l = m+1
      col[1] = pcv;
      int ti = (m + 2) * (m + 3) / 2 + m;       // tri(m+2)+m
      for (int l = m + 2; l <= MAXDEG; ++l) {
        float av = TB.ab[ti][0], bv = TB.ab[ti][1];
        float pn = av * (x * pcv) - bv * p2;
        p2 = pcv; pcv = pn;
        col[l - m] = pn;
        ti += l + 1;
      }
    }
  }

  // intra-wave fence: all LDS writes visible before cross-lane reads
  asm volatile("s_waitcnt lgkmcnt(0)" ::: "memory");
  __builtin_amdgcn_sched_barrier(0);

  // ---- gather + product, float4 store (ranks 4*ln..4*ln+3) ----
  #pragma unroll
  for (int p = 0; p < WPTS; ++p) {
    const int n = n0 + p;
    if (n < N) {
      const float* tA = tab + (2 * p) * TS;
      const float* gA = tg  + (2 * p) * GS;
      const float* tB = tab + (2 * p + 1) * TS;
      const float* gB = tg  + (2 * p + 1) * GS;
      float v[4];
      #pragma unroll
      for (int c2 = 0; c2 < 4; ++c2) {
        int pi = wi[c2] & 0xffff, ti2 = ((unsigned)wi[c2]) >> 16;
        int pj = wj[c2] & 0xffff, tj2 = ((unsigned)wj[c2]) >> 16;
        v[c2] = (tA[pi] * gA[ti2]) * (tB[pj] * gB[tj2]);
      }
      *reinterpret_cast<float4*>(out + (size_t)n * RANK + 4 * ln) =
          make_float4(v[0], v[1], v[2], v[3]);
    }
  }
}

extern "C" void kernel_launch(void* const* d_in, const int* in_sizes, int n_in,
                              void* d_out, int out_size, void* d_ws, size_t ws_size,
                              hipStream_t stream) {
  const float* coords = (const float*)d_in[0];
  const int*   ri     = (const int*)d_in[1];
  const int*   rj     = (const int*)d_in[2];
  float*       out    = (float*)d_out;
  const int N = in_sizes[0] / 6;
  int2* w = nullptr;
  if (d_ws && ws_size >= RANK * sizeof(int2)) {
    w = (int2*)d_ws;
    sh_prep<<<1, RANK, 0, stream>>>(ri, rj, w);
  }
  const int grid = (N + PPB - 1) / PPB;
  sh_fused<<<grid, 256, 0, stream>>>(coords, ri, rj, w, out, N);
}

// Round 5
// 356.288 us; speedup vs baseline: 1.0484x; 1.0484x over previous
//
#include <hip/hip_runtime.h>
#include <math.h>

#define MAXDEG 20
#define NM 21               // m = 0..20
#define RANK 256
#define PPB 8               // points per block
#define NSLOT 16            // (point,side) slots per block (power of 2)
#define TS 233              // Legendre slot stride in words (231 used; 233%32=9 -> spread)
#define HDRS 65             // header stride (65%32=1 -> conflict-free pd-parallel access)

// LDS layout (19072 B total -> 8 blocks/CU):
//   s_tab[slot][row] : Pbar_{l,m}, row = base(m)+(l-m), base(m)=21m-m(m-1)/2
//   s_hdr[slot][.]   : [0..20]=cos(m phi) [21..41]=sin(m phi) [42..62]=Pmm seeds [63]=x
//   Y_{l,+m} = tab[row]*hdr[m];  Y_{l,-m} = tab[row]*hdr[21+m]  (hdr[0]=1 covers m=0)

// ---- compile-time sqrt (Newton, double) for __constant__ tables ----
constexpr double csqrt(double x) {
  double g = x < 1.0 ? 1.0 : x;
  for (int i = 0; i < 80; ++i) g = 0.5 * (g + x / g);
  return g;
}

struct Tabs {
  float ab[231][2];   // normalized recurrence coeffs, index tri(l)+m = l(l+1)/2+m
  float c1[NM];       // sqrt(2m+3)
  constexpr Tabs() : ab{}, c1{} {
    for (int l = 0; l <= MAXDEG; ++l)
      for (int m = 0; m <= l; ++m) {
        int i = l * (l + 1) / 2 + m;
        double a = 0.0, b = 0.0;
        if (l >= m + 2) {
          double l2 = (double)l * l, m2 = (double)m * m;
          double inv = 1.0 / (l2 - m2);
          a = csqrt((4.0 * l2 - 1.0) * inv);
          b = csqrt((2.0 * l + 1.0) * ((double)(l - 1) * (l - 1) - m2)
                    / (2.0 * l - 3.0) * inv);
        }
        ab[i][0] = (float)a; ab[i][1] = (float)b;
      }
    for (int m = 0; m <= MAXDEG; ++m) c1[m] = (float)csqrt(2.0 * m + 3.0);
  }
};
__constant__ Tabs TB{};

// flax index k = l*(l+1)+m -> (Legendre row pi, trig row ti)
__device__ __forceinline__ void remap2(int k, int& pi, int& ti) {
  int l = (int)sqrtf((float)k);
  if (l * l > k) --l;
  if ((l + 1) * (l + 1) <= k) ++l;
  int m = k - l * (l + 1);
  int am = m < 0 ? -m : m;
  pi = 21 * am - (am * (am - 1)) / 2 + (l - am);
  ti = (m == 0) ? 0 : (m > 0 ? am : 21 + am);
}

// prep: remap the 256 (i,j) rank pairs once, packed pi|(ti<<16)
__global__ void sh_prep(const int* __restrict__ ri, const int* __restrict__ rj,
                        int2* __restrict__ w) {
  int t = threadIdx.x;
  int pi, ti, pj, tj;
  remap2(ri[t], pi, ti);
  remap2(rj[t], pj, tj);
  w[t] = make_int2(pi | (ti << 16), pj | (tj << 16));
}

__global__ __launch_bounds__(256, 8)
void sh_fused(const float* __restrict__ coords,
              const int* __restrict__ rand_i,
              const int* __restrict__ rand_j,
              const int2* __restrict__ w,
              float* __restrict__ out, int N) {
  __shared__ float s_tab[NSLOT * TS];
  __shared__ float s_hdr[NSLOT * HDRS];

  const int t  = threadIdx.x;
  const int n0 = blockIdx.x * PPB;

  // ---- gather indices for rank t (thread t = rank t) ----
  int wi, wj;
  if (w) {
    int2 a = w[t];
    wi = a.x; wj = a.y;
  } else {
    int pi, ti, pj, tj;
    remap2(rand_i[t], pi, ti);
    remap2(rand_j[t], pj, tj);
    wi = pi | (ti << 16);
    wj = pj | (tj << 16);
  }

  // ---- phase 0: once-per-slot header (16 lanes of wave 0; serial m-chain) ----
  if (t < NSLOT) {
    int p = t >> 1, d = t & 1;
    int n = n0 + p; if (n >= N) n = N - 1;
    const float* c = coords + (size_t)n * 6 + d * 3;
    float cx = c[0], cy = c[1], cz = c[2];
    float x = cz * rsqrtf(cx * cx + cy * cy + cz * cz);  // cos(inclination)
    x = fminf(1.f, fmaxf(-1.f, x));
    float s = sqrtf(fmaxf(0.f, 1.f - x * x));            // sin(inclination) >= 0
    float rho2 = cx * cx + cy * cy;
    float cphi = 1.f, sphi = 0.f;
    if (rho2 > 0.f) { float ir = rsqrtf(rho2); cphi = cx * ir; sphi = cy * ir; }
    float* h = s_hdr + t * HDRS;
    float cm = 1.f, sm = 0.f;
    float pmm = 0.28209479177387814f;                    // sqrt(1/(4*pi)) = Pbar_00
    h[0] = 1.f; h[21] = 0.f; h[42] = pmm; h[63] = x;
    #pragma unroll
    for (int m = 1; m <= MAXDEG; ++m) {
      float cn = cm * cphi - sm * sphi;                  // incremental rotation
      float sn = sm * cphi + cm * sphi;
      cm = cn; sm = sn;
      // literal after unroll -> sqrtf folds at compile time
      float df = -sqrtf((2.f * (float)m + 1.f) / (2.f * (float)m));  // CS phase
      if (m == 1) df *= 1.41421356237309515f;            // fold sqrt(2) for m>=1
      pmm = df * s * pmm;
      h[m] = cm; h[21 + m] = sm; h[42 + m] = pmm;
    }
  }
  __syncthreads();

  // ---- phase 1: fill Legendre tables. 336 tasks = (m, slot), m-major ----
  for (int task = t; task < NM * NSLOT; task += 256) {
    const int m  = task >> 4;          // NSLOT = 16
    const int sl = task & 15;
    const float* h = s_hdr + sl * HDRS;
    float x  = h[63];
    float p1 = h[42 + m];
    float* col = s_tab + sl * TS + (21 * m - (m * (m - 1)) / 2);
    col[0] = p1;                                  // l = m
    if (m < MAXDEG) {
      float p2 = p1;
      float pc = TB.c1[m] * x * p1;               // l = m+1
      col[1] = pc;
      int ti = (m + 2) * (m + 3) / 2 + m;         // tri(m+2)+m
      for (int l = m + 2; l <= MAXDEG; ++l) {
        float av = TB.ab[ti][0], bv = TB.ab[ti][1];
        float pn = av * (x * pc) - bv * p2;
        p2 = pc; pc = pn;
        col[l - m] = pn;
        ti += l + 1;
      }
    }
  }
  __syncthreads();

  // ---- phase 2: gathered products (4 b32 reads/point), coalesced store ----
  const int pi = wi & 0xffff, ti = ((unsigned)wi) >> 16;
  const int pj = wj & 0xffff, tj = ((unsigned)wj) >> 16;
  if (n0 + PPB <= N) {
    #pragma unroll
    for (int p = 0; p < PPB; ++p) {
      float av = s_tab[(2 * p) * TS + pi]     * s_hdr[(2 * p) * HDRS + ti];
      float bv = s_tab[(2 * p + 1) * TS + pj] * s_hdr[(2 * p + 1) * HDRS + tj];
      out[(size_t)(n0 + p) * RANK + t] = av * bv;
    }
  } else {
    for (int p = 0; p < PPB; ++p) {
      int n = n0 + p;
      if (n < N) {
        float av = s_tab[(2 * p) * TS + pi]     * s_hdr[(2 * p) * HDRS + ti];
        float bv = s_tab[(2 * p + 1) * TS + pj] * s_hdr[(2 * p + 1) * HDRS + tj];
        out[(size_t)n * RANK + t] = av * bv;
      }
    }
  }
}

extern "C" void kernel_launch(void* const* d_in, const int* in_sizes, int n_in,
                              void* d_out, int out_size, void* d_ws, size_t ws_size,
                              hipStream_t stream) {
  const float* coords = (const float*)d_in[0];
  const int*   ri     = (const int*)d_in[1];
  const int*   rj     = (const int*)d_in[2];
  float*       out    = (float*)d_out;
  const int N = in_sizes[0] / 6;
  int2* w = nullptr;
  if (d_ws && ws_size >= RANK * sizeof(int2)) {
    w = (int2*)d_ws;
    sh_prep<<<1, RANK, 0, stream>>>(ri, rj, w);
  }
  const int grid = (N + PPB - 1) / PPB;
  sh_fused<<<grid, 256, 0, stream>>>(coords, ri, rj, w, out, N);
}